// Round 6
// baseline (337.749 us; speedup 1.0000x reference)
//
#include <hip/hip_runtime.h>

typedef __attribute__((ext_vector_type(8))) __bf16 bf16x8;
typedef __attribute__((ext_vector_type(4))) __bf16 bf16x4;
typedef __attribute__((ext_vector_type(4))) float floatx4;

#define MFMA16x16x32 __builtin_amdgcn_mfma_f32_16x16x32_bf16

// async 16B/lane global->LDS; LDS dest = wave-uniform base + lane*16.
__device__ __forceinline__ void async_load16(const void* g, void* l) {
  __builtin_amdgcn_global_load_lds((const __attribute__((address_space(1))) void*)g,
                                   (__attribute__((address_space(3))) void*)l, 16, 0, 0);
}

// ---------------- merged cast fp32 -> bf16 for all 5 inputs ----------------
__global__ __launch_bounds__(256) void cast_all_kernel(const float* __restrict__ x,
                                                       const float* __restrict__ wq,
                                                       const float* __restrict__ wk,
                                                       const float* __restrict__ wv,
                                                       const float* __restrict__ wo,
                                                       __bf16* __restrict__ dst) {
  int i = blockIdx.x * blockDim.x + threadIdx.x;  // float4 units
  const float* src;
  int off;
  if (i < 2097152)      { src = x;  off = 0; }
  else if (i < 3145728) { src = wq; off = 2097152; }
  else if (i < 3407872) { src = wk; off = 3145728; }
  else if (i < 3670016) { src = wv; off = 3407872; }
  else                  { src = wo; off = 3670016; }
  float4 v = ((const float4*)src)[i - off];
  bf16x4 o;
  o[0] = (__bf16)v.x; o[1] = (__bf16)v.y; o[2] = (__bf16)v.z; o[3] = (__bf16)v.w;
  *(bf16x4*)(dst + (size_t)i * 4) = o;
}

// ---------------- GEMM: C(M,N) = A(M,K) @ B(N,K)^T, bf16 in ----------------
// 256 x BN tile, 8 waves (2M x 4N), BK=64. Phased K-loop (T3+T4+T5): per K-tile,
// entry {vmcnt(0) (free: loads issued a full tile ago) -> barrier -> issue next
// tile's DMA into idle buffer}, then 4 phases of {4-7 ds_read_b128 -> barrier ->
// lgkmcnt(0)+sched_barrier -> setprio(1) 8-12 MFMA setprio(0) -> barrier}.
// The fine interleave lets LDS-read issue of one wave overlap MFMA of the other
// wave on the same SIMD (m196/m201 mechanism); setprio pays only in this regime.
// MODE 0: fp32 C store. MODE 1: fused epilogue (RoPE Q/K + LDS-transposed V).
template <int MODE, int BN>
__global__ __launch_bounds__(512, 1) void gemm_bt(const __bf16* __restrict__ A,
                                                  const __bf16* __restrict__ Bw,
                                                  float* __restrict__ C,
                                                  const float* __restrict__ cs,
                                                  const float* __restrict__ sn,
                                                  __bf16* __restrict__ qb,
                                                  __bf16* __restrict__ kb,
                                                  __bf16* __restrict__ vtg,
                                                  int M, int N, int K) {
  constexpr int NW = BN / 4;        // per-wave N extent (48 or 32)
  constexpr int NF = NW / 16;       // n-frags per wave (3 or 2)
  constexpr int NBI = BN / 64;      // B staging instrs per wave (3 or 2)
  __shared__ __bf16 As[2][256][64];
  __shared__ __bf16 Bs[2][BN][64];
  const int tid = threadIdx.x;
  const int wave = tid >> 6, lane = tid & 63;
  const int quad = lane >> 4, l16 = lane & 15;
  const int wm2 = wave >> 2, wn4 = wave & 3;       // 2M x 4N wave grid
  const int lr = lane >> 3, ls = lane & 7;
  const int segg = ls ^ lr;

  // bijective XCD swizzle (gridDim.x % 8 == 0 for both call sites)
  const int nwg = gridDim.x;
  const int wg = (blockIdx.x & 7) * (nwg >> 3) + (blockIdx.x >> 3);
  const int GY = M >> 8;
  const int by = wg % GY, bx = wg / GY;
  const int row0 = by * 256, col0 = bx * BN;

  floatx4 acc[8][NF] = {};
  const __bf16* Ab = A + (size_t)row0 * K + segg * 8;
  const __bf16* Bb = Bw + (size_t)col0 * K + segg * 8;

  auto stage = [&](int sb, int k0) {
#pragma unroll
    for (int i = 0; i < 4; i++)
      async_load16(Ab + (size_t)(wave * 32 + i * 8 + lr) * K + k0,
                   &As[sb][wave * 32 + i * 8][0]);
#pragma unroll
    for (int j = 0; j < NBI; j++)
      async_load16(Bb + (size_t)(wave * (BN / 8) + j * 8 + lr) * K + k0,
                   &Bs[sb][wave * (BN / 8) + j * 8][0]);
  };

  const int NS = K >> 6;
  stage(0, 0);  // K-tile 0 -> buf0; retire guarded by t=0 entry vmcnt+barrier

#pragma unroll 2
  for (int t = 0; t < NS; t++) {
    const int c = t & 1;
    // entry: my tile-t loads were issued >= 1 full K-tile ago -> ~free drain
    asm volatile("s_waitcnt vmcnt(0)" ::: "memory");
    asm volatile("s_barrier" ::: "memory");        // all waves' slices resident
    if (t + 1 < NS) stage(c ^ 1, (t + 1) * 64);    // DMA into idle buffer
    bf16x8 bfr[2][NF];
#pragma unroll
    for (int kk = 0; kk < 2; kk++) {
#pragma unroll
      for (int mh = 0; mh < 2; mh++) {
        // ---- phase (kk, mh): ds_reads ----
        bf16x8 af[4];
        if (mh == 0) {
#pragma unroll
          for (int nt = 0; nt < NF; nt++) {
            int row = wn4 * NW + nt * 16 + l16;
            int seg = (kk * 4 + quad) ^ (row & 7);
            bfr[kk][nt] = *(const bf16x8*)&Bs[c][row][seg * 8];
          }
        }
#pragma unroll
        for (int mi = 0; mi < 4; mi++) {
          int row = wm2 * 128 + (mh * 4 + mi) * 16 + l16;
          int seg = (kk * 4 + quad) ^ (row & 7);
          af[mi] = *(const bf16x8*)&As[c][row][seg * 8];
        }
        asm volatile("s_barrier" ::: "memory");
        asm volatile("s_waitcnt lgkmcnt(0)" ::: "memory");
        __builtin_amdgcn_sched_barrier(0);  // rule #18: pin MFMA below the wait
        __builtin_amdgcn_s_setprio(1);
#pragma unroll
        for (int mi = 0; mi < 4; mi++)
#pragma unroll
          for (int nt = 0; nt < NF; nt++)
            acc[mh * 4 + mi][nt] =
                MFMA16x16x32(af[mi], bfr[kk][nt], acc[mh * 4 + mi][nt], 0, 0, 0);
        __builtin_amdgcn_s_setprio(0);
        asm volatile("s_barrier" ::: "memory");
      }
    }
  }

  if (MODE == 0) {
#pragma unroll
    for (int mt = 0; mt < 8; mt++)
#pragma unroll
      for (int nt = 0; nt < NF; nt++)
#pragma unroll
        for (int r = 0; r < 4; r++) {
          int row = row0 + wm2 * 128 + mt * 16 + quad * 4 + r;
          int col = col0 + wn4 * NW + nt * 16 + l16;
          C[(size_t)row * N + col] = acc[mt][nt][r];
        }
  } else {
    // ---- Q / K epilogue (RoPE; Q pre-scaled by (1/sqrt(128))*log2(e)) ----
#pragma unroll
    for (int mt = 0; mt < 8; mt++)
#pragma unroll
      for (int nt = 0; nt < NF; nt++) {
        const int cbase = col0 + wn4 * NW + nt * 16;  // uniform per (wave,nt)
        if (cbase < 2560) {
          const int c = cbase + l16;
#pragma unroll
          for (int r = 0; r < 4; r++) {
            int row = row0 + wm2 * 128 + mt * 16 + quad * 4 + r;
            int t = row & 2047;
            float v = acc[mt][nt][r];
            float vp = __shfl_xor(v, 1);  // RoPE pair partner (col ^ 1)
            int i = (c & 127) >> 1;
            float co = cs[t * 64 + i], si = sn[t * 64 + i];
            float rv = v * co + ((c & 1) ? vp : -vp) * si;
            if (cbase < 2048) {
              qb[(size_t)row * 2048 + c] = (__bf16)(rv * 0.1275411391f);
            } else {
              kb[(size_t)row * 512 + c - 2048] = (__bf16)rv;
            }
          }
        }
      }
    // ---- V epilogue: per-wave LDS transpose -> contiguous 16B stores ----
    // As is dead: last tile's entry vmcnt(0) drained all DMA; every wave's
    // reads completed before its final phase barrier.
    __bf16* Vl = &As[0][0][0] + wave * 2048;  // [16 vd][128 t]
    const int brow = row0 + wm2 * 128;        // 128 rows, single batch
    const int bb = brow >> 11, trow = brow & 2047;
#pragma unroll
    for (int nt = 0; nt < NF; nt++) {
      const int cbase = col0 + wn4 * NW + nt * 16;
      if (cbase >= 2560) {
#pragma unroll
        for (int mt = 0; mt < 8; mt++)
#pragma unroll
          for (int r = 0; r < 4; r++)
            Vl[l16 * 128 + mt * 16 + quad * 4 + r] = (__bf16)acc[mt][nt][r];
        asm volatile("" ::: "memory");
        const int vB = cbase - 2560;
#pragma unroll
        for (int p = 0; p < 4; p++) {
          int vd = p * 4 + (lane >> 4);
          int t0 = (lane & 15) * 8;
          bf16x8 val = *(const bf16x8*)&Vl[vd * 128 + t0];
          *(bf16x8*)&vtg[((size_t)bb * 512 + vB + vd) * 2048 + trow + t0] = val;
        }
        asm volatile("" ::: "memory");
      }
    }
  }
}

// ---------------- Flash attention, causal, GQA; double-buffered K/V ----------------
// Proven R3 version (77.5 us): counted-vmcnt pipeline, hoisted swizzled LDS bases.
__global__ __launch_bounds__(256, 2) void attn_kernel(const __bf16* __restrict__ qb,
                                                      const __bf16* __restrict__ kb,
                                                      const __bf16* __restrict__ vtg,
                                                      __bf16* __restrict__ yb) {
  const int id = blockIdx.x;
  const int q1 = id >> 8;              // 0..1
  const int cc = id & 255;
  const int kvh = cc & 3;
  const int b = (cc >> 2) & 1;
  const int s5 = (cc >> 3) & 31;
  const int tile = q1 ? (63 - s5) : s5;  // bijective over 0..63; pairs co-resident
  const int tid = threadIdx.x, wave = tid >> 6, lane = tid & 63;
  const int h = kvh * 4 + wave;
  const int quad = lane >> 4, l16 = lane & 15;
  const int q0 = tile * 32;
  __shared__ __bf16 Ks[2][64][128];      // [buf][key][dim], swizzled (32 KB)
  __shared__ __bf16 Vt[2][128][64];      // [buf][dim][key], swizzled (32 KB)
  __shared__ __bf16 Ps[4][2][16][64];    // per-wave, per-m-tile P strip (16 KB)
  const __bf16* kbase = kb + (size_t)b * 2048 * 512 + kvh * 128;
  const __bf16* vbase = vtg + ((size_t)b * 512 + kvh * 128) * 2048;

  // ---- hoisted lane-dependent LDS byte bases (loop-invariant) ----
  const int u16   = (quad ^ (l16 & 3)) * 16;
  const int b2_64 = (l16 & 4) ? 64 : 0;
  char* const ksb = (char*)Ks;
  char* const vtb = (char*)Vt;
  char* const psb = (char*)Ps + wave * 4096;
  char* const kA0 = ksb + l16 * 256 + u16 + b2_64;   // K frag, kc even, buf0
  char* const kB0 = kA0 + 64 - 2 * b2_64;            // K frag, kc odd,  buf0
  char* const kA1 = kA0 + 16384;
  char* const kB1 = kB0 + 16384;
  char* const vA0 = vtb + l16 * 128 + u16 + b2_64;   // V frag, c2=0, buf0
  char* const vB0 = vA0 + 64 - 2 * b2_64;            // V frag, c2=1, buf0
  char* const vA1 = vA0 + 16384;
  char* const vB1 = vB0 + 16384;
  char* const prA = psb + l16 * 128 + u16 + b2_64;   // Ps read, c2=0 (+mt*2048)
  char* const prB = prA + 64 - 2 * b2_64;            // Ps read, c2=1
  const int h16 = (l16 & 8) ? 16 : 0;
  const int q64 = (quad & 1) * 64;
  char* const pw00 = psb + quad * 512 + (l16 & 7) * 2 + h16 + q64;         // r even, nt<2
  char* const pw10 = psb + quad * 512 + (l16 & 7) * 2 + (16 - h16) + q64;  // r odd,  nt<2
  char* const pw01 = pw00 + 64 - 2 * q64;                                  // r even, nt>=2
  char* const pw11 = pw10 + 64 - 2 * q64;                                  // r odd,  nt>=2

  // ---- hoisted staging source pointers (global) ----
  const int klr4 = lane >> 4, kls = lane & 15;
  const int vlr8 = lane >> 3, vls = lane & 7;
  const __bf16* ksrc[4];
  const __bf16* vsrc[4];
#pragma unroll
  for (int i = 0; i < 4; i++) {
    int row = (wave * 4 + i) * 4 + klr4;
    ksrc[i] = kbase + (size_t)row * 512 + (kls ^ (row & 7)) * 8;
    int d = (wave * 4 + i) * 8 + vlr8;
    vsrc[i] = vbase + (size_t)d * 2048 + (vls ^ (d & 7)) * 8;
  }
  char* const kdst = ksb + wave * 4096;
  char* const vdst = vtb + wave * 4096;

  auto stage = [&](int pb, int s0) {
#pragma unroll
    for (int i = 0; i < 4; i++)   // K: 64 keys x 128 dims
      async_load16(ksrc[i] + (size_t)s0 * 512, kdst + pb * 16384 + i * 1024);
#pragma unroll
    for (int i = 0; i < 4; i++)   // Vt: 128 dims x 64 keys
      async_load16(vsrc[i] + s0, vdst + pb * 16384 + i * 1024);
  };

  bf16x8 qf[2][4];
#pragma unroll
  for (int mt = 0; mt < 2; mt++)
#pragma unroll
    for (int kc = 0; kc < 4; kc++)
      qf[mt][kc] = *(const bf16x8*)(qb + (size_t)(b * 2048 + q0 + mt * 16 + l16) * 2048 +
                                    h * 128 + kc * 32 + quad * 8);
  bf16x8 ones;
#pragma unroll
  for (int j = 0; j < 8; j++) ones[j] = (__bf16)1.0f;
  floatx4 o[2][8] = {};
  floatx4 lsum[2] = {};
  const int nblocks = (tile + 2) >> 1;  // ceil((q0+32)/64)

  stage(0, 0);  // prologue; residency enforced by iter-0 vmcnt+barrier

  for (int it = 0; it < nblocks; it++) {
    const int cur = it & 1;
    const int s0 = it * 64;
    // (a) all waves done READING buf[cur^1] (prev iter) -> safe to DMA into it
    asm volatile("s_barrier" ::: "memory");
    if (it + 1 < nblocks) {
      stage(cur ^ 1, s0 + 64);  // prefetch next tile; stays in flight over compute
      asm volatile("s_waitcnt vmcnt(8)" ::: "memory");  // my buf[cur] loads retired
    } else {
      asm volatile("s_waitcnt vmcnt(0)" ::: "memory");
    }
    // (b) every wave's buf[cur] slice resident
    asm volatile("s_barrier" ::: "memory");
    const char* kA = cur ? kA1 : kA0;
    const char* kB = cur ? kB1 : kB0;
    const char* vA = cur ? vA1 : vA0;
    const char* vB = cur ? vB1 : vB0;
    // QK^T: 32 q rows x 64 keys (K-frags shared by both m-tiles)
    floatx4 sacc[2][4] = {};
    __builtin_amdgcn_s_setprio(1);
#pragma unroll
    for (int kc = 0; kc < 4; kc++) {
      const char* kbp = (kc & 1) ? kB : kA;
      bf16x8 bfr[4];
#pragma unroll
      for (int nt = 0; nt < 4; nt++)
        bfr[nt] = *(const bf16x8*)(kbp + nt * 4096 + (kc >> 1) * 128);
#pragma unroll
      for (int mt = 0; mt < 2; mt++)
#pragma unroll
        for (int nt = 0; nt < 4; nt++)
          sacc[mt][nt] = MFMA16x16x32(qf[mt][kc], bfr[nt], sacc[mt][nt], 0, 0, 0);
    }
    __builtin_amdgcn_s_setprio(0);
    // P = exp2(S) (scale pre-folded into Q), masked on diagonal block
    const bool diag = (it == nblocks - 1);
#pragma unroll
    for (int mt = 0; mt < 2; mt++)
#pragma unroll
      for (int r = 0; r < 4; r++) {
        const int qg = q0 + mt * 16 + quad * 4 + r;
#pragma unroll
        for (int nt = 0; nt < 4; nt++) {
          float p = __builtin_exp2f(sacc[mt][nt][r]);
          if (diag) { int keyg = s0 + nt * 16 + l16; p = (keyg <= qg) ? p : 0.f; }
          char* w = (r & 1) ? ((nt < 2) ? pw10 : pw11) : ((nt < 2) ? pw00 : pw01);
          *(__bf16*)(w + mt * 2048 + r * 128 + ((nt & 1) ^ (r >> 1)) * 32) = (__bf16)p;
        }
      }
    // P @ V (+ ones for row sums). Same-wave Ps write->read: no barrier.
    __builtin_amdgcn_s_setprio(1);
#pragma unroll
    for (int c2 = 0; c2 < 2; c2++) {
      const char* pr = c2 ? prB : prA;
      const char* vv = c2 ? vB : vA;
      bf16x8 pa[2];
#pragma unroll
      for (int mt = 0; mt < 2; mt++) {
        pa[mt] = *(const bf16x8*)(pr + mt * 2048);
        lsum[mt] = MFMA16x16x32(pa[mt], ones, lsum[mt], 0, 0, 0);
      }
#pragma unroll
      for (int dt = 0; dt < 8; dt++) {
        bf16x8 vf = *(const bf16x8*)(vv + dt * 2048);
#pragma unroll
        for (int mt = 0; mt < 2; mt++)
          o[mt][dt] = MFMA16x16x32(pa[mt], vf, o[mt][dt], 0, 0, 0);
      }
    }
    __builtin_amdgcn_s_setprio(0);
  }
#pragma unroll
  for (int mt = 0; mt < 2; mt++) {
    float inv[4];
#pragma unroll
    for (int r = 0; r < 4; r++) inv[r] = 1.f / lsum[mt][r];
#pragma unroll
    for (int dt = 0; dt < 8; dt++)
#pragma unroll
      for (int r = 0; r < 4; r++) {
        int qg = q0 + mt * 16 + quad * 4 + r;
        yb[(size_t)(b * 2048 + qg) * 2048 + h * 128 + dt * 16 + l16] =
            (__bf16)(o[mt][dt][r] * inv[r]);
      }
  }
}

// ---------------- host ----------------
extern "C" void kernel_launch(void* const* d_in, const int* in_sizes, int n_in,
                              void* d_out, int out_size, void* d_ws, size_t ws_size,
                              hipStream_t stream) {
  const float* x  = (const float*)d_in[0];
  const float* fc = (const float*)d_in[1];
  const float* fs = (const float*)d_in[2];
  const float* wq = (const float*)d_in[3];
  const float* wk = (const float*)d_in[4];
  const float* wv = (const float*)d_in[5];
  const float* wo = (const float*)d_in[6];
  float* out = (float*)d_out;
  char* ws = (char*)d_ws;

  __bf16* xb   = (__bf16*)(ws);              // 4096x2048 bf16
  __bf16* wqkv = (__bf16*)(ws + 16777216);   // 3072x2048 bf16 (wq|wk|wv)
  __bf16* wob  = (__bf16*)(ws + 29360128);   // 2048x2048 bf16
  __bf16* qbuf = (__bf16*)(ws + 37748736);   // 4096x2048 bf16 (roped, pre-scaled)
  __bf16* kbuf = (__bf16*)(ws + 54525952);   // 4096x512 bf16 (roped)
  __bf16* vtg  = (__bf16*)(ws + 58720256);   // 1024x2048 bf16 (V^T per b,kvh)
  __bf16* ybuf = (__bf16*)(ws + 62914560);   // 4096x2048 bf16

  // one merged cast launch (dst regions contiguous from ws+0)
  cast_all_kernel<<<18432, 256, 0, stream>>>(x, wq, wk, wv, wo, xb);

  // QKV projection, 256x192 tiles -> 256 WGs (1/CU), phased K-loop
  gemm_bt<1, 192><<<256, 512, 0, stream>>>(xb, wqkv, nullptr, fc, fs,
                                           qbuf, kbuf, vtg, 4096, 3072, 2048);

  // flash attention: 512 4-wave WGs, 32 q-rows/wave, counted-vmcnt pipeline
  attn_kernel<<<512, 256, 0, stream>>>(qbuf, kbuf, vtg, ybuf);

  // output projection, 256x128 tiles -> 256 WGs (1/CU), phased K-loop
  gemm_bt<0, 128><<<256, 512, 0, stream>>>(ybuf, wob, out, nullptr, nullptr,
                                           nullptr, nullptr, nullptr, 4096, 2048, 2048);
}

// Round 7
// 303.169 us; speedup vs baseline: 1.1141x; 1.1141x over previous
//
#include <hip/hip_runtime.h>

typedef __attribute__((ext_vector_type(8))) __bf16 bf16x8;
typedef __attribute__((ext_vector_type(4))) __bf16 bf16x4;
typedef __attribute__((ext_vector_type(4))) float floatx4;

#define MFMA16x16x32 __builtin_amdgcn_mfma_f32_16x16x32_bf16

// async 16B/lane global->LDS; LDS dest = wave-uniform base + lane*16.
__device__ __forceinline__ void async_load16(const void* g, void* l) {
  __builtin_amdgcn_global_load_lds((const __attribute__((address_space(1))) void*)g,
                                   (__attribute__((address_space(3))) void*)l, 16, 0, 0);
}

// ---------------- merged cast fp32 -> bf16 for all 5 inputs ----------------
__global__ __launch_bounds__(256) void cast_all_kernel(const float* __restrict__ x,
                                                       const float* __restrict__ wq,
                                                       const float* __restrict__ wk,
                                                       const float* __restrict__ wv,
                                                       const float* __restrict__ wo,
                                                       __bf16* __restrict__ dst) {
  int i = blockIdx.x * blockDim.x + threadIdx.x;  // float4 units
  const float* src;
  int off;
  if (i < 2097152)      { src = x;  off = 0; }
  else if (i < 3145728) { src = wq; off = 2097152; }
  else if (i < 3407872) { src = wk; off = 3145728; }
  else if (i < 3670016) { src = wv; off = 3407872; }
  else                  { src = wo; off = 3670016; }
  float4 v = ((const float4*)src)[i - off];
  bf16x4 o;
  o[0] = (__bf16)v.x; o[1] = (__bf16)v.y; o[2] = (__bf16)v.z; o[3] = (__bf16)v.w;
  *(bf16x4*)(dst + (size_t)i * 4) = o;
}

// ---------------- GEMM: C(M,N) = A(M,K) @ B(N,K)^T, bf16 in (R5, proven) -----------
// 256 x BN tile, 8 waves (2M x 4N), BK=64, counted-vmcnt 2-K-step-ahead pipeline.
// MODE 0: fp32 C store. MODE 1: fused epilogue (RoPE Q/K + LDS-transposed V).
template <int MODE, int BN>
__global__ __launch_bounds__(512, 1) void gemm_bt(const __bf16* __restrict__ A,
                                                  const __bf16* __restrict__ Bw,
                                                  float* __restrict__ C,
                                                  const float* __restrict__ cs,
                                                  const float* __restrict__ sn,
                                                  __bf16* __restrict__ qb,
                                                  __bf16* __restrict__ kb,
                                                  __bf16* __restrict__ vtg,
                                                  int M, int N, int K) {
  constexpr int NW = BN / 4;        // per-wave N extent (48 or 32)
  constexpr int NF = NW / 16;       // n-frags per wave (3 or 2)
  constexpr int NBI = BN / 64;      // B staging instrs per wave (3 or 2)
  __shared__ __bf16 As[2][256][64];
  __shared__ __bf16 Bs[2][BN][64];
  const int tid = threadIdx.x;
  const int wave = tid >> 6, lane = tid & 63;
  const int quad = lane >> 4, l16 = lane & 15;
  const int wm2 = wave >> 2, wn4 = wave & 3;       // 2M x 4N wave grid
  const int lr = lane >> 3, ls = lane & 7;
  const int segg = ls ^ lr;

  // bijective XCD swizzle (gridDim.x % 8 == 0 for both call sites)
  const int nwg = gridDim.x;
  const int wg = (blockIdx.x & 7) * (nwg >> 3) + (blockIdx.x >> 3);
  const int GY = M >> 8;
  const int by = wg % GY, bx = wg / GY;
  const int row0 = by * 256, col0 = bx * BN;

  floatx4 acc[8][NF] = {};
  const __bf16* Ab = A + (size_t)row0 * K + segg * 8;
  const __bf16* Bb = Bw + (size_t)col0 * K + segg * 8;

  auto stage = [&](int sb, int k0) {
#pragma unroll
    for (int i = 0; i < 4; i++)
      async_load16(Ab + (size_t)(wave * 32 + i * 8 + lr) * K + k0,
                   &As[sb][wave * 32 + i * 8][0]);
#pragma unroll
    for (int j = 0; j < NBI; j++)
      async_load16(Bb + (size_t)(wave * (BN / 8) + j * 8 + lr) * K + k0,
                   &Bs[sb][wave * (BN / 8) + j * 8][0]);
  };

  const int NS = K >> 6;
  stage(0, 0);
  stage(1, 64);

#pragma unroll 2
  for (int s = 0; s < NS; s++) {
    const int c = s & 1;
    // counted wait: newest (4+NBI) loads (= stage(s+1)) may remain in flight;
    // everything older (incl. stage(s)) has landed. Last iter: full drain.
    if (s == NS - 1) {
      asm volatile("s_waitcnt vmcnt(0)" ::: "memory");
    } else if constexpr (NBI == 3) {
      asm volatile("s_waitcnt vmcnt(7)" ::: "memory");
    } else {
      asm volatile("s_waitcnt vmcnt(6)" ::: "memory");
    }
    __builtin_amdgcn_s_barrier();  // (a) all waves' buf[c] slices resident

    bf16x8 af[2][8], bfr[2][NF];
#pragma unroll
    for (int kk = 0; kk < 2; kk++) {
#pragma unroll
      for (int mt = 0; mt < 8; mt++) {
        int row = wm2 * 128 + mt * 16 + l16;
        int seg = (kk * 4 + quad) ^ (row & 7);
        af[kk][mt] = *(const bf16x8*)&As[c][row][seg * 8];
      }
#pragma unroll
      for (int nt = 0; nt < NF; nt++) {
        int row = wn4 * NW + nt * 16 + l16;
        int seg = (kk * 4 + quad) ^ (row & 7);
        bfr[kk][nt] = *(const bf16x8*)&Bs[c][row][seg * 8];
      }
    }
    asm volatile("s_waitcnt lgkmcnt(0)" ::: "memory");  // frags in regs
    __builtin_amdgcn_s_barrier();  // (b) ALL waves done reading buf[c]
    if (s + 2 < NS) stage(c, (s + 2) * 64);  // DMA into freed buf[c]
    __builtin_amdgcn_s_setprio(1);
#pragma unroll
    for (int kk = 0; kk < 2; kk++)
#pragma unroll
      for (int mt = 0; mt < 8; mt++)
#pragma unroll
        for (int nt = 0; nt < NF; nt++)
          acc[mt][nt] = MFMA16x16x32(af[kk][mt], bfr[kk][nt], acc[mt][nt], 0, 0, 0);
    __builtin_amdgcn_s_setprio(0);
  }

  if (MODE == 0) {
#pragma unroll
    for (int mt = 0; mt < 8; mt++)
#pragma unroll
      for (int nt = 0; nt < NF; nt++)
#pragma unroll
        for (int r = 0; r < 4; r++) {
          int row = row0 + wm2 * 128 + mt * 16 + quad * 4 + r;
          int col = col0 + wn4 * NW + nt * 16 + l16;
          C[(size_t)row * N + col] = acc[mt][nt][r];
        }
  } else {
    // ---- Q / K epilogue (RoPE; Q pre-scaled by (1/sqrt(128))*log2(e)) ----
#pragma unroll
    for (int mt = 0; mt < 8; mt++)
#pragma unroll
      for (int nt = 0; nt < NF; nt++) {
        const int cbase = col0 + wn4 * NW + nt * 16;  // uniform per (wave,nt)
        if (cbase < 2560) {
          const int c = cbase + l16;
#pragma unroll
          for (int r = 0; r < 4; r++) {
            int row = row0 + wm2 * 128 + mt * 16 + quad * 4 + r;
            int t = row & 2047;
            float v = acc[mt][nt][r];
            float vp = __shfl_xor(v, 1);  // RoPE pair partner (col ^ 1)
            int i = (c & 127) >> 1;
            float co = cs[t * 64 + i], si = sn[t * 64 + i];
            float rv = v * co + ((c & 1) ? vp : -vp) * si;
            if (cbase < 2048) {
              qb[(size_t)row * 2048 + c] = (__bf16)(rv * 0.1275411391f);
            } else {
              kb[(size_t)row * 512 + c - 2048] = (__bf16)rv;
            }
          }
        }
      }
    // ---- V epilogue: per-wave LDS transpose -> contiguous 16B stores ----
    __bf16* Vl = &As[0][0][0] + wave * 2048;  // [16 vd][128 t]
    const int brow = row0 + wm2 * 128;        // 128 rows, single batch
    const int bb = brow >> 11, trow = brow & 2047;
#pragma unroll
    for (int nt = 0; nt < NF; nt++) {
      const int cbase = col0 + wn4 * NW + nt * 16;
      if (cbase >= 2560) {
#pragma unroll
        for (int mt = 0; mt < 8; mt++)
#pragma unroll
          for (int r = 0; r < 4; r++)
            Vl[l16 * 128 + mt * 16 + quad * 4 + r] = (__bf16)acc[mt][nt][r];
        asm volatile("" ::: "memory");
        const int vB = cbase - 2560;
#pragma unroll
        for (int p = 0; p < 4; p++) {
          int vd = p * 4 + (lane >> 4);
          int t0 = (lane & 15) * 8;
          bf16x8 val = *(const bf16x8*)&Vl[vd * 128 + t0];
          *(bf16x8*)&vtg[((size_t)bb * 512 + vB + vd) * 2048 + trow + t0] = val;
        }
        asm volatile("" ::: "memory");
      }
    }
  }
}

// ---------------- Flash attention: 1024 WGs, intra-WG KV-split, causal GQA ----------
// WG = (tile, b, kvh, head-pair): 4 waves = 2 heads x 2 KV-chunks, KVBLK=32.
// Chunk0 = blocks [0,c0), chunk1 = [c0,nkb) (incl. diagonal). All waves run L1
// iters (uniform barrier count); chunk0 masks surplus iters. LPT: long tiles
// dispatch first; 1024-WG queue backfills (vs 512 = capacity, no backfill).
// LDS 72KB -> 2 WGs/CU; launch_bounds(256,2) -> 256 VGPR cap (no spill).
// K: gload_lds + counted vmcnt(4) (R3 schedule). V: reg-staged w/ swizzled
// ds_write (R4's verified seg formula). Intra-WG merge via dead Ks/Vt.
__global__ __launch_bounds__(256, 2) void attn_kernel(const __bf16* __restrict__ qb,
                                                      const __bf16* __restrict__ kb,
                                                      const __bf16* __restrict__ vtg,
                                                      __bf16* __restrict__ yb) {
  const int id = blockIdx.x;
  const int kvh = id & 3, b = (id >> 2) & 1;   // id&7 -> XCD-local K/V group
  const int pair = (id >> 3) & 1;
  const int tile = 63 - (id >> 4);             // LPT: longest tiles first
  const int tid = threadIdx.x, wave = tid >> 6, lane = tid & 63;
  const int ck = wave >> 1, hw = wave & 1;     // KV-chunk, head-within-pair
  const int h = kvh * 4 + pair * 2 + hw;
  const int quad = lane >> 4, l16 = lane & 15;
  const int q0 = tile * 32;
  const int nkb = tile + 1;                    // 32-key blocks total
  const int c0 = nkb >> 1;                     // chunk0: [0,c0)
  const int L1 = nkb - c0;                     // chunk1: [c0,nkb); L1 in [1,32]

  __shared__ __bf16 Ks[2][64][128];   // [buf][ck*32+key][dim] swizzled (32 KB)
  __shared__ __bf16 Vt[2][128][64];   // [buf][dim][ck*32+key] swizzled (32 KB)
  __shared__ __bf16 Ps[4][2][16][32]; // per-wave, per-mt P strip (8 KB)

  const __bf16* kbase = kb + (size_t)b * 2048 * 512 + kvh * 128;
  const __bf16* vbase = vtg + ((size_t)b * 512 + kvh * 128) * 2048;

  // ---- K staging (gload_lds): 4 loads/wave, rows ck*32 + hw*16 + j*4 + lr4 ----
  const int klr4 = lane >> 4, kls = lane & 15;
  const __bf16* ksrc[4];
  char* kdst[4];
#pragma unroll
  for (int j = 0; j < 4; j++) {
    int lrow = hw * 16 + j * 4 + klr4;  // local row within chunk [0,32)
    ksrc[j] = kbase + (size_t)lrow * 512 + (kls ^ (lrow & 7)) * 8;
    kdst[j] = (char*)Ks + (ck * 32 + hw * 16 + j * 4) * 256;
  }
  // ---- V staging (reg + swizzled ds_write): 4 loads + 4 writes/wave ----
  const int vdl = lane >> 2, vks = lane & 3;
  const __bf16* vsrc[4];
  char* vdst[4];
#pragma unroll
  for (int j = 0; j < 4; j++) {
    int d = hw * 64 + j * 16 + vdl;
    vsrc[j] = vbase + (size_t)d * 2048 + vks * 8;
    vdst[j] = (char*)Vt + d * 128 + (((ck * 4 + vks) ^ (d & 7)) * 16);
  }

  // ---- hoisted compute bases ----
  const int u16 = (quad ^ (l16 & 3)) * 16;
  const int b2_64 = (l16 & 4) ? 64 : 0;
  char* const kA0 = (char*)Ks + (ck * 32 + l16) * 256 + u16 + b2_64;  // kc even
  char* const kB0 = kA0 + 64 - 2 * b2_64;                             // kc odd
  char* const vrd0 = (char*)Vt + l16 * 128 + u16 + (((ck ^ (l16 >> 2)) & 1) ? 64 : 0);
  char* const psb = (char*)Ps + wave * 2048;
  char* const prd = psb + l16 * 64 + u16;                             // + mt*1024
  const int h3 = (l16 >> 3) & 1;
  char* const pwE = psb + quad * 256 + (l16 & 7) * 2 + h3 * 16;       // r even
  char* const pwO = psb + quad * 256 + (l16 & 7) * 2 + 16 - h3 * 16;  // r odd

  bf16x8 qf[2][4];
#pragma unroll
  for (int mt = 0; mt < 2; mt++)
#pragma unroll
    for (int kc = 0; kc < 4; kc++)
      qf[mt][kc] = *(const bf16x8*)(qb + (size_t)(b * 2048 + q0 + mt * 16 + l16) * 2048 +
                                    h * 128 + kc * 32 + quad * 8);
  bf16x8 ones;
#pragma unroll
  for (int j = 0; j < 8; j++) ones[j] = (__bf16)1.0f;
  floatx4 o[2][8] = {};
  floatx4 lsum[2] = {};

  // ---- prologue: stage own chunk's first block into buf 0 ----
  {
    const int g0 = ck ? c0 : 0;  // c0==0 -> chunk0 stages blk0 (masked later)
#pragma unroll
    for (int j = 0; j < 4; j++)
      async_load16(ksrc[j] + (size_t)g0 * 32 * 512, kdst[j]);
    bf16x8 vr[4];
#pragma unroll
    for (int j = 0; j < 4; j++) vr[j] = *(const bf16x8*)(vsrc[j] + g0 * 32);
#pragma unroll
    for (int j = 0; j < 4; j++) *(bf16x8*)(vdst[j]) = vr[j];  // auto vmcnt wait
  }

  for (int it = 0; it < L1; it++) {
    const int cur = it & 1;
    const int bc = cur << 14, bn = (cur ^ 1) << 14;
    asm volatile("s_waitcnt lgkmcnt(0)" ::: "memory");  // publish my V ds_writes
    asm volatile("s_barrier" ::: "memory");  // (A) all waves done reading buf[cur^1]
    const bool pf = (it + 1 < L1);
    int gn = 0;
    if (pf) {
      gn = ck ? (c0 + it + 1) : min(it + 1, c0 > 0 ? c0 - 1 : 0);
#pragma unroll
      for (int j = 0; j < 4; j++)
        async_load16(ksrc[j] + (size_t)gn * 32 * 512, kdst[j] + bn);
      asm volatile("s_waitcnt vmcnt(4)" ::: "memory");  // K(it) retired
    } else {
      asm volatile("s_waitcnt vmcnt(0)" ::: "memory");
    }
    asm volatile("s_barrier" ::: "memory");  // (B) buf[cur] resident, V published

    // ---- QK^T: 32 q rows x 32 keys ----
    floatx4 sacc[2][2] = {};
    __builtin_amdgcn_s_setprio(1);
#pragma unroll
    for (int kc = 0; kc < 4; kc++) {
      const char* kp = ((kc & 1) ? kB0 : kA0) + bc + (kc >> 1) * 128;
      bf16x8 bf0 = *(const bf16x8*)(kp);
      bf16x8 bf1 = *(const bf16x8*)(kp + 4096);
#pragma unroll
      for (int mt = 0; mt < 2; mt++) {
        sacc[mt][0] = MFMA16x16x32(qf[mt][kc], bf0, sacc[mt][0], 0, 0, 0);
        sacc[mt][1] = MFMA16x16x32(qf[mt][kc], bf1, sacc[mt][1], 0, 0, 0);
      }
    }
    __builtin_amdgcn_s_setprio(0);

    // V(it+1) global loads issued mid-iter; latency hides under softmax+PV
    bf16x8 vr[4];
    if (pf) {
#pragma unroll
      for (int j = 0; j < 4; j++) vr[j] = *(const bf16x8*)(vsrc[j] + gn * 32);
    }

    // ---- softmax: P = exp2(S) (scale pre-folded in Q), masked ----
    const int gq = ck ? (c0 + it) : it;
    const bool diag = (ck == 1) && (it == L1 - 1);
    const bool inval = (ck == 0) && (it >= c0);
#pragma unroll
    for (int mt = 0; mt < 2; mt++)
#pragma unroll
      for (int r = 0; r < 4; r++) {
        const int qg = q0 + mt * 16 + quad * 4 + r;
#pragma unroll
        for (int nt = 0; nt < 2; nt++) {
          float p = __builtin_exp2f(sacc[mt][nt][r]);
          if (diag) { int keyg = gq * 32 + nt * 16 + l16; p = (keyg <= qg) ? p : 0.f; }
          if (inval) p = 0.f;
          char* w = (r & 1) ? pwO : pwE;
          *(__bf16*)(w + mt * 1024 + r * 64 + ((nt ^ ((r >> 1) & 1)) & 1) * 32) =
              (__bf16)p;
        }
      }

    // ---- P @ V (+ ones for row sums); same-wave Ps write->read ----
    __builtin_amdgcn_s_setprio(1);
    bf16x8 pa[2];
#pragma unroll
    for (int mt = 0; mt < 2; mt++) {
      pa[mt] = *(const bf16x8*)(prd + mt * 1024);
      lsum[mt] = MFMA16x16x32(pa[mt], ones, lsum[mt], 0, 0, 0);
    }
#pragma unroll
    for (int dt = 0; dt < 8; dt++) {
      bf16x8 vf = *(const bf16x8*)(vrd0 + bc + dt * 2048);
      o[0][dt] = MFMA16x16x32(pa[0], vf, o[0][dt], 0, 0, 0);
      o[1][dt] = MFMA16x16x32(pa[1], vf, o[1][dt], 0, 0, 0);
    }
    __builtin_amdgcn_s_setprio(0);

    // V(it+1) regs -> Vt[cur^1] (targets buffer not read this iter)
    if (pf) {
#pragma unroll
      for (int j = 0; j < 4; j++) *(bf16x8*)(vdst[j] + bn) = vr[j];
    }
  }

  // ---- intra-WG merge: chunk1 publishes via dead Ks/Vt, chunk0 finalizes ----
  asm volatile("s_barrier" ::: "memory");  // all compute done; Ks/Vt dead
  {
    char* mo = (char*)Ks + hw * 16384;   // 16KB per publishing wave
    char* ml = (char*)Vt + hw * 2048;    // 2KB per publishing wave
    if (ck == 1) {
#pragma unroll
      for (int mt = 0; mt < 2; mt++) {
#pragma unroll
        for (int dt = 0; dt < 8; dt++)
          *(floatx4*)(mo + ((mt * 8 + dt) * 64 + lane) * 16) = o[mt][dt];
        *(floatx4*)(ml + (mt * 64 + lane) * 16) = lsum[mt];
      }
    }
    asm volatile("s_waitcnt lgkmcnt(0)" ::: "memory");
    asm volatile("s_barrier" ::: "memory");
    if (ck == 0) {
#pragma unroll
      for (int mt = 0; mt < 2; mt++) {
        lsum[mt] += *(const floatx4*)(ml + (mt * 64 + lane) * 16);
        float inv[4];
#pragma unroll
        for (int r = 0; r < 4; r++) inv[r] = 1.f / lsum[mt][r];
#pragma unroll
        for (int dt = 0; dt < 8; dt++) {
          floatx4 op = *(const floatx4*)(mo + ((mt * 8 + dt) * 64 + lane) * 16);
#pragma unroll
          for (int r = 0; r < 4; r++) {
            int qg = q0 + mt * 16 + quad * 4 + r;
            yb[(size_t)(b * 2048 + qg) * 2048 + h * 128 + dt * 16 + l16] =
                (__bf16)((o[mt][dt][r] + op[r]) * inv[r]);
          }
        }
      }
    }
  }
}

// ---------------- host ----------------
extern "C" void kernel_launch(void* const* d_in, const int* in_sizes, int n_in,
                              void* d_out, int out_size, void* d_ws, size_t ws_size,
                              hipStream_t stream) {
  const float* x  = (const float*)d_in[0];
  const float* fc = (const float*)d_in[1];
  const float* fs = (const float*)d_in[2];
  const float* wq = (const float*)d_in[3];
  const float* wk = (const float*)d_in[4];
  const float* wv = (const float*)d_in[5];
  const float* wo = (const float*)d_in[6];
  float* out = (float*)d_out;
  char* ws = (char*)d_ws;

  __bf16* xb   = (__bf16*)(ws);              // 4096x2048 bf16
  __bf16* wqkv = (__bf16*)(ws + 16777216);   // 3072x2048 bf16 (wq|wk|wv)
  __bf16* wob  = (__bf16*)(ws + 29360128);   // 2048x2048 bf16
  __bf16* qbuf = (__bf16*)(ws + 37748736);   // 4096x2048 bf16 (roped, pre-scaled)
  __bf16* kbuf = (__bf16*)(ws + 54525952);   // 4096x512 bf16 (roped)
  __bf16* vtg  = (__bf16*)(ws + 58720256);   // 1024x2048 bf16 (V^T per b,kvh)
  __bf16* ybuf = (__bf16*)(ws + 62914560);   // 4096x2048 bf16

  // one merged cast launch (dst regions contiguous from ws+0)
  cast_all_kernel<<<18432, 256, 0, stream>>>(x, wq, wk, wv, wo, xb);

  // QKV projection, 256x192 tiles -> 256 WGs (1/CU), counted-vmcnt pipeline (R5)
  gemm_bt<1, 192><<<256, 512, 0, stream>>>(xb, wqkv, nullptr, fc, fs,
                                           qbuf, kbuf, vtg, 4096, 3072, 2048);

  // flash attention: 1024 WGs x 4 waves (2 heads x 2 KV-chunks), LPT + backfill
  attn_kernel<<<1024, 256, 0, stream>>>(qbuf, kbuf, vtg, ybuf);

  // output projection, 256x128 tiles -> 256 WGs (1/CU), counted-vmcnt pipeline (R5)
  gemm_bt<0, 128><<<256, 512, 0, stream>>>(ybuf, wob, out, nullptr, nullptr,
                                           nullptr, nullptr, nullptr, 4096, 2048, 2048);
}